// Round 15
// baseline (948.611 us; speedup 1.0000x reference)
//
#include <hip/hip_runtime.h>

#define NA_ 131072
#define NN  262144
#define EE  1048576
#define RR  4
#define EPS_ 1e-5f

typedef unsigned short ushort_t;
typedef unsigned char uchar_t;
typedef unsigned int uint_t;
typedef __attribute__((ext_vector_type(8))) short bf16x8;
typedef __attribute__((ext_vector_type(4))) float f32x4;

__device__ __forceinline__ float bf2f(uint_t u16) {
    return __uint_as_float(u16 << 16);
}
__device__ __forceinline__ uint_t f2bf(float f) {
    uint_t x = __float_as_uint(f);
    return (x + 0x7fffu + ((x >> 16) & 1u)) >> 16;   // RNE
}

// async global->LDS DMA, 16 B per lane; LDS dest is base + lane*16 (wave-
// uniform base), but the SOURCE address is per-lane -> swizzle lives there.
__device__ __forceinline__ void gl2lds16(const void* g, void* l) {
    __builtin_amdgcn_global_load_lds(
        (const __attribute__((address_space(1))) void*)g,
        (__attribute__((address_space(3))) void*)l, 16, 0, 0);
}

// ---------------------------------------------------------------------------
// Input projection GEMM: C[M x 128] = relu(A[M x 64] @ B + b)
// ---------------------------------------------------------------------------
__global__ __launch_bounds__(256) void proj_gemm(const float* __restrict__ A,
                                                 const short* __restrict__ Btg,
                                                 const float* __restrict__ bias,
                                                 ushort_t* __restrict__ C) {
    const int K = 64;
    __shared__ short As[128][K + 8];
    __shared__ short Bs[128][K + 8];
    const int tid  = threadIdx.x;
    const int lane = tid & 63;
    const int l15  = lane & 15;
    const int q    = lane >> 4;
    const int wv   = tid >> 6;
    const int wr   = (wv >> 1) * 64;
    const int wc   = (wv & 1) * 64;
    const size_t blockRow = (size_t)blockIdx.x * 128;

    #pragma unroll
    for (int it = 0; it < 4; it++) {
        int sidx = (it * 256 + tid) * 8;
        int row = sidx / K, col = sidx % K;
        const float* Ag = A + (blockRow + row) * K + col;
        float4 v0 = *(const float4*)Ag;
        float4 v1 = *(const float4*)(Ag + 4);
        uint4 u;
        u.x = f2bf(v0.x) | (f2bf(v0.y) << 16);
        u.y = f2bf(v0.z) | (f2bf(v0.w) << 16);
        u.z = f2bf(v1.x) | (f2bf(v1.y) << 16);
        u.w = f2bf(v1.z) | (f2bf(v1.w) << 16);
        *(uint4*)&As[row][col] = u;
        *(uint4*)&Bs[row][col] = *(const uint4*)(Btg + (size_t)row * K + col);
    }
    __syncthreads();

    f32x4 acc[4][4];
    #pragma unroll
    for (int i = 0; i < 4; i++)
        #pragma unroll
        for (int j = 0; j < 4; j++) {
            acc[i][j][0] = 0.f; acc[i][j][1] = 0.f;
            acc[i][j][2] = 0.f; acc[i][j][3] = 0.f;
        }

    #pragma unroll
    for (int kk = 0; kk < 2; kk++) {
        bf16x8 af[4], bfr[4];
        #pragma unroll
        for (int i = 0; i < 4; i++)
            af[i] = *(const bf16x8*)&As[wr + i * 16 + l15][kk * 32 + q * 8];
        #pragma unroll
        for (int j = 0; j < 4; j++)
            bfr[j] = *(const bf16x8*)&Bs[wc + j * 16 + l15][kk * 32 + q * 8];
        #pragma unroll
        for (int i = 0; i < 4; i++)
            #pragma unroll
            for (int j = 0; j < 4; j++)
                acc[i][j] = __builtin_amdgcn_mfma_f32_16x16x32_bf16(
                    af[i], bfr[j], acc[i][j], 0, 0, 0);
    }

    #pragma unroll
    for (int j = 0; j < 4; j++) {
        int gcol = wc + j * 16 + l15;
        float bv = bias[gcol];
        #pragma unroll
        for (int i = 0; i < 4; i++) {
            size_t rbase = blockRow + wr + i * 16 + q * 4;
            #pragma unroll
            for (int r = 0; r < 4; r++) {
                float v = fmaxf(acc[i][j][r] + bv, 0.f);
                C[(rbase + r) * 128 + gcol] = (ushort_t)f2bf(v);
            }
        }
    }
}

// ---------------------------------------------------------------------------
// Weight prep. Input-proj: [n][64]. Layer weights: plain chunk-major
// [kc][n][128] (kc 0..3 = rel, 4 = root). Swizzle is applied at DMA time.
// ---------------------------------------------------------------------------
__global__ void prep_weights(const float* __restrict__ Wia,
                             const float* __restrict__ Wiw,
                             const float* __restrict__ Wroot,
                             const float* __restrict__ Wrel,
                             short* __restrict__ wt) {
    int e = blockIdx.x * 256 + threadIdx.x;
    if (e < 8192) {
        int k = e >> 7, n = e & 127;
        wt[n * 64 + k] = (short)f2bf(Wia[e]);
    } else if (e < 16384) {
        int t = e - 8192;
        int k = t >> 7, n = t & 127;
        wt[8192 + n * 64 + k] = (short)f2bf(Wiw[t]);
    } else {
        int t = e - 16384;           // 0 .. 163839
        int l = t / 81920;
        int d = t % 81920;
        int kc = d / 16384;
        int rem2 = d % 16384;
        int n = rem2 >> 7;
        int kkk = rem2 & 127;
        float val = (kc < 4)
            ? Wrel[(((size_t)l * 4 + kc) * 128 + kkk) * 128 + n]
            : Wroot[((size_t)l * 128 + kkk) * 128 + n];
        wt[16384 + (size_t)l * 81920 + kc * 16384 + n * 128 + kkk] =
            (short)f2bf(val);
    }
}

// ---------------------------------------------------------------------------
// CSR build. Packed 8-bit per-relation counts; 4 edges/thread for atomic ILP
// (4 independent atomics in flight amortize the ~500-cycle round trip).
// ---------------------------------------------------------------------------
__global__ void count_edges(const int* __restrict__ dstv,
                            const int* __restrict__ et,
                            uint_t* __restrict__ cntp,
                            uchar_t* __restrict__ rank) {
    int base = blockIdx.x * 1024 + threadIdx.x;
    int e0 = base, e1 = base + 256, e2 = base + 512, e3 = base + 768;
    int r0 = et[e0], r1 = et[e1], r2 = et[e2], r3 = et[e3];
    int d0 = dstv[e0], d1 = dstv[e1], d2 = dstv[e2], d3 = dstv[e3];
    uint_t o0 = atomicAdd(&cntp[d0], 1u << (8 * r0));
    uint_t o1 = atomicAdd(&cntp[d1], 1u << (8 * r1));
    uint_t o2 = atomicAdd(&cntp[d2], 1u << (8 * r2));
    uint_t o3 = atomicAdd(&cntp[d3], 1u << (8 * r3));
    rank[e0] = (uchar_t)((o0 >> (8 * r0)) & 0xffu);
    rank[e1] = (uchar_t)((o1 >> (8 * r1)) & 0xffu);
    rank[e2] = (uchar_t)((o2 >> (8 * r2)) & 0xffu);
    rank[e3] = (uchar_t)((o3 >> (8 * r3)) & 0xffu);
}

__global__ void inv_deg(uint_t* __restrict__ cntp, float* __restrict__ inv,
                        int* __restrict__ deg) {
    int i = blockIdx.x * 256 + threadIdx.x;
    if (i < NN) {
        uint_t c = cntp[i];
        int c0 = c & 255, c1 = (c >> 8) & 255, c2 = (c >> 16) & 255, c3 = c >> 24;
        inv[i]          = 1.0f / (float)(c0 > 1 ? c0 : 1);
        inv[NN + i]     = 1.0f / (float)(c1 > 1 ? c1 : 1);
        inv[2 * NN + i] = 1.0f / (float)(c2 > 1 ? c2 : 1);
        inv[3 * NN + i] = 1.0f / (float)(c3 > 1 ? c3 : 1);
        deg[i] = c0 + c1 + c2 + c3;
        cntp[i] = ((uint_t)c0 << 8) | ((uint_t)(c0 + c1) << 16)
                | ((uint_t)(c0 + c1 + c2) << 24);
    }
}

__global__ void scan1(const int* __restrict__ deg, int* __restrict__ offs,
                      int* __restrict__ bsum) {
    __shared__ int lds[256];
    int tid = threadIdx.x;
    int i = blockIdx.x * 256 + tid;
    int v = deg[i];
    int incl = v;
    lds[tid] = incl;
    __syncthreads();
    for (int off = 1; off < 256; off <<= 1) {
        int t = (tid >= off) ? lds[tid - off] : 0;
        __syncthreads();
        incl += t;
        lds[tid] = incl;
        __syncthreads();
    }
    offs[i] = incl - v;
    if (tid == 255) bsum[blockIdx.x] = incl;
}

__global__ void scan_bsum(int* __restrict__ bsum) {
    __shared__ int lds[256];
    int tid = threadIdx.x;
    int t0 = bsum[tid * 4 + 0], t1 = bsum[tid * 4 + 1];
    int t2 = bsum[tid * 4 + 2], t3 = bsum[tid * 4 + 3];
    int s = t0 + t1 + t2 + t3;
    int incl = s;
    lds[tid] = incl;
    __syncthreads();
    for (int off = 1; off < 256; off <<= 1) {
        int t = (tid >= off) ? lds[tid - off] : 0;
        __syncthreads();
        incl += t;
        lds[tid] = incl;
        __syncthreads();
    }
    int e = incl - s;
    bsum[tid * 4 + 0] = e;
    bsum[tid * 4 + 1] = e + t0;
    bsum[tid * 4 + 2] = e + t0 + t1;
    bsum[tid * 4 + 3] = e + t0 + t1 + t2;
}

__global__ void scan_add(int* __restrict__ offs, const int* __restrict__ bsum) {
    int i = blockIdx.x * 256 + threadIdx.x;
    offs[i] = offs[i] + bsum[blockIdx.x];
    if (i == 0) offs[NN] = EE;
}

__global__ void place_edges(const int* __restrict__ srcv,
                            const int* __restrict__ dstv,
                            const int* __restrict__ et,
                            const uchar_t* __restrict__ rank,
                            const int* __restrict__ offs,
                            const uint_t* __restrict__ pref,
                            uint_t* __restrict__ pk) {
    int base = blockIdx.x * 1024 + threadIdx.x;
    #pragma unroll
    for (int t = 0; t < 4; t++) {
        int e = base + t * 256;
        int d = dstv[e], r = et[e];
        int pos = offs[d] + (int)((pref[d] >> (8 * r)) & 255u) + (int)rank[e];
        pk[pos] = (uint_t)srcv[e] | ((uint_t)r << 18);
    }
}

// ---------------------------------------------------------------------------
// Pull aggregation: one wave per dst node. 8/4-wide batched gathers keep
// memory ILP; the per-edge relation is WAVE-UNIFORM (all lanes read the same
// pk[e]), so readfirstlane + scalar switch replaces the 8-way cndmask chain
// (~17 VALU/edge -> ~4). M plane-major, coalesced writes.
// ---------------------------------------------------------------------------
__global__ __launch_bounds__(256) void agg_means(const uint_t* __restrict__ pk,
                                                 const int* __restrict__ offs,
                                                 const ushort_t* __restrict__ hold,
                                                 const float* __restrict__ inv,
                                                 ushort_t* __restrict__ M,
                                                 int lo, int rowsCap) {
    int idx = blockIdx.x * 4 + (threadIdx.x >> 6);
    int d = lo + idx;
    int lane = threadIdx.x & 63;
    int beg = offs[d], end = offs[d + 1];

    float a0x = 0.f, a0y = 0.f, a1x = 0.f, a1y = 0.f;
    float a2x = 0.f, a2y = 0.f, a3x = 0.f, a3y = 0.f;

    auto accu = [&](uint_t p, uint_t hv) {
        float x = bf2f(hv & 0xffffu), y = bf2f(hv >> 16);
        int r = __builtin_amdgcn_readfirstlane((int)(p >> 18));
        switch (r) {
        case 0:  a0x += x; a0y += y; break;
        case 1:  a1x += x; a1y += y; break;
        case 2:  a2x += x; a2y += y; break;
        default: a3x += x; a3y += y; break;
        }
    };

    int e = beg;
    for (; e + 8 <= end; e += 8) {
        uint_t p[8], v[8];
        #pragma unroll
        for (int t = 0; t < 8; t++) p[t] = pk[e + t];
        #pragma unroll
        for (int t = 0; t < 8; t++)
            v[t] = ((const uint_t*)(hold + (size_t)(p[t] & 0x3FFFFu) * 128))[lane];
        #pragma unroll
        for (int t = 0; t < 8; t++) accu(p[t], v[t]);
    }
    for (; e + 4 <= end; e += 4) {
        uint_t p0 = pk[e], p1 = pk[e + 1], p2 = pk[e + 2], p3 = pk[e + 3];
        uint_t v0 = ((const uint_t*)(hold + (size_t)(p0 & 0x3FFFFu) * 128))[lane];
        uint_t v1 = ((const uint_t*)(hold + (size_t)(p1 & 0x3FFFFu) * 128))[lane];
        uint_t v2 = ((const uint_t*)(hold + (size_t)(p2 & 0x3FFFFu) * 128))[lane];
        uint_t v3 = ((const uint_t*)(hold + (size_t)(p3 & 0x3FFFFu) * 128))[lane];
        accu(p0, v0); accu(p1, v1); accu(p2, v2); accu(p3, v3);
    }
    for (; e < end; e++) {
        uint_t p = pk[e];
        uint_t v = ((const uint_t*)(hold + (size_t)(p & 0x3FFFFu) * 128))[lane];
        accu(p, v);
    }

    float w0 = inv[d], w1 = inv[NN + d], w2 = inv[2 * NN + d], w3 = inv[3 * NN + d];
    uint_t* P = (uint_t*)M;
    size_t planeU = (size_t)rowsCap * 64;
    size_t rowU = (size_t)idx * 64 + lane;
    P[rowU]              = f2bf(a0x * w0) | (f2bf(a0y * w0) << 16);
    P[planeU + rowU]     = f2bf(a1x * w1) | (f2bf(a1y * w1) << 16);
    P[2 * planeU + rowU] = f2bf(a2x * w2) | (f2bf(a2y * w2) << 16);
    P[3 * planeU + rowU] = f2bf(a3x * w3) | (f2bf(a3y * w3) << 16);
}

// ---------------------------------------------------------------------------
// Layer GEMM + LN + ReLU (+ optional fused head). Tile BM=64 x BN=128,
// 49.5 KB LDS -> 3 blocks/CU (r13-verified win). Source-side XOR DMA
// swizzle -> conflict-free ds_reads (r12-verified: conflicts = 0).
// ---------------------------------------------------------------------------
template<bool HEAD>
__global__ __launch_bounds__(256) void layer_gemm_ln(
    const ushort_t* __restrict__ Mg,
    const ushort_t* __restrict__ hold,
    const short* __restrict__ Btg,       // [5][128 n][128 k] chunk-major
    const float* __restrict__ bconv,
    const float* __restrict__ lng,
    const float* __restrict__ lnb,
    ushort_t* __restrict__ hnew,
    const float* __restrict__ Wout,
    const float* __restrict__ bout,
    const float* __restrict__ basep,
    float* __restrict__ pred,
    int lo, int rowsCap) {
    __shared__ short As[64 * 128];       // 16 KB
    __shared__ short Bs[128 * 128];      // 32 KB
    __shared__ float lds_s[64][2], lds_q[64][2], lds_h[64][2];

    const int tid  = threadIdx.x;
    const int lane = tid & 63;
    const int l15  = lane & 15;
    const int q    = lane >> 4;
    const int wv   = tid >> 6;
    const int wr   = (wv >> 1) * 32;     // 2 row-bands of 32
    const int wc   = (wv & 1) * 64;      // 2 col-bands of 64
    const int blockRowL = blockIdx.x * 64;
    const size_t planeS = (size_t)rowsCap * 128;

    f32x4 acc[2][4];
    #pragma unroll
    for (int i = 0; i < 2; i++)
        #pragma unroll
        for (int j = 0; j < 4; j++) {
            acc[i][j][0] = 0.f; acc[i][j][1] = 0.f;
            acc[i][j][2] = 0.f; acc[i][j][3] = 0.f;
        }

    // per-lane source offset with XOR group swizzle (r12-verified).
    const int rloc = lane >> 4;
    const int gsw  = (lane & 15) ^ ((wv * 4 + rloc) & 15);
    const int lby  = (rloc << 8) + (gsw << 4);

    for (int kc = 0; kc < 5; kc++) {
        const char* asrc = (kc < 4)
            ? (const char*)(Mg + (size_t)kc * planeS + (size_t)blockRowL * 128)
            : (const char*)(hold + (size_t)(lo + blockRowL) * 128);
        const char* bsrc = (const char*)(Btg + (size_t)kc * 16384);
        __syncthreads();
        #pragma unroll
        for (int it = 0; it < 8; it++) {
            int off = it * 4096 + wv * 1024;
            if (it < 4) gl2lds16(asrc + off + lby, (char*)As + off);
            gl2lds16(bsrc + off + lby, (char*)Bs + off);
        }
        __syncthreads();

        #pragma unroll
        for (int kk = 0; kk < 4; kk++) {
            bf16x8 af[2], bfr[4];
            #pragma unroll
            for (int i = 0; i < 2; i++)
                af[i] = *(const bf16x8*)
                    &As[(wr + i * 16 + l15) * 128 + (((kk * 4 + q) ^ l15) << 3)];
            #pragma unroll
            for (int j = 0; j < 4; j++)
                bfr[j] = *(const bf16x8*)
                    &Bs[(wc + j * 16 + l15) * 128 + (((kk * 4 + q) ^ l15) << 3)];
            #pragma unroll
            for (int i = 0; i < 2; i++)
                #pragma unroll
                for (int j = 0; j < 4; j++)
                    acc[i][j] = __builtin_amdgcn_mfma_f32_16x16x32_bf16(
                        af[i], bfr[j], acc[i][j], 0, 0, 0);
        }
    }

    // ---- epilogue: + b_conv, LayerNorm, affine, ReLU (+ head dot) ----
    float bj[4], gj[4], bbj[4], wj[4];
    #pragma unroll
    for (int j = 0; j < 4; j++) {
        int col = wc + j * 16 + l15;
        bj[j]  = bconv[col];
        gj[j]  = lng[col];
        bbj[j] = lnb[col];
        if (HEAD) wj[j] = Wout[col];
    }
    #pragma unroll
    for (int i = 0; i < 2; i++)
        #pragma unroll
        for (int j = 0; j < 4; j++)
            #pragma unroll
            for (int r = 0; r < 4; r++) acc[i][j][r] += bj[j];

    float ps[2][4], pq[2][4];
    #pragma unroll
    for (int i = 0; i < 2; i++)
        #pragma unroll
        for (int r = 0; r < 4; r++) {
            float s = 0.f, qq = 0.f;
            #pragma unroll
            for (int j = 0; j < 4; j++) {
                float v = acc[i][j][r];
                s += v;
                qq += v * v;
            }
            ps[i][r] = s;
            pq[i][r] = qq;
        }
    #pragma unroll
    for (int m = 1; m <= 8; m <<= 1)
        #pragma unroll
        for (int i = 0; i < 2; i++)
            #pragma unroll
            for (int r = 0; r < 4; r++) {
                ps[i][r] += __shfl_xor(ps[i][r], m);
                pq[i][r] += __shfl_xor(pq[i][r], m);
            }

    if (l15 == 0) {
        #pragma unroll
        for (int i = 0; i < 2; i++)
            #pragma unroll
            for (int r = 0; r < 4; r++) {
                int row = wr + i * 16 + q * 4 + r;
                lds_s[row][wv & 1] = ps[i][r];
                lds_q[row][wv & 1] = pq[i][r];
            }
    }
    __syncthreads();

    float hs[2][4];
    #pragma unroll
    for (int i = 0; i < 2; i++)
        #pragma unroll
        for (int r = 0; r < 4; r++) {
            int row = wr + i * 16 + q * 4 + r;
            float sum = lds_s[row][0] + lds_s[row][1];
            float sq  = lds_q[row][0] + lds_q[row][1];
            float mu  = sum * (1.0f / 128.0f);
            float var = sq * (1.0f / 128.0f) - mu * mu;
            float rs  = rsqrtf(var + EPS_);
            size_t gr = (size_t)(lo + blockRowL + row) * 128;
            float hd = 0.f;
            #pragma unroll
            for (int j = 0; j < 4; j++) {
                float v = (acc[i][j][r] - mu) * rs * gj[j] + bbj[j];
                v = fmaxf(v, 0.f);
                if (HEAD) hd += v * wj[j];
                else hnew[gr + wc + j * 16 + l15] = (ushort_t)f2bf(v);
            }
            if (HEAD) hs[i][r] = hd;
        }

    if (HEAD) {
        #pragma unroll
        for (int m = 1; m <= 8; m <<= 1)
            #pragma unroll
            for (int i = 0; i < 2; i++)
                #pragma unroll
                for (int r = 0; r < 4; r++)
                    hs[i][r] += __shfl_xor(hs[i][r], m);
        if (l15 == 0) {
            #pragma unroll
            for (int i = 0; i < 2; i++)
                #pragma unroll
                for (int r = 0; r < 4; r++) {
                    int row = wr + i * 16 + q * 4 + r;
                    lds_h[row][wv & 1] = hs[i][r];
                }
        }
        __syncthreads();
        if (tid < 64)
            pred[lo + blockRowL + tid] =
                lds_h[tid][0] + lds_h[tid][1] + bout[0] + basep[0];
    }
}

// ---------------------------------------------------------------------------
extern "C" void kernel_launch(void* const* d_in, const int* in_sizes, int n_in,
                              void* d_out, int out_size, void* d_ws, size_t ws_size,
                              hipStream_t stream) {
    const float* x_a    = (const float*)d_in[0];
    const float* x_w    = (const float*)d_in[1];
    const int*   eidx   = (const int*)d_in[2];
    const int*   etype  = (const int*)d_in[3];
    const float* W_in_a = (const float*)d_in[4];
    const float* b_in_a = (const float*)d_in[5];
    const float* W_in_w = (const float*)d_in[6];
    const float* b_in_w = (const float*)d_in[7];
    const float* W_rel  = (const float*)d_in[8];
    const float* W_root = (const float*)d_in[9];
    const float* b_conv = (const float*)d_in[10];
    const float* ln_g   = (const float*)d_in[11];
    const float* ln_b   = (const float*)d_in[12];
    const float* W_out  = (const float*)d_in[13];
    const float* b_out  = (const float*)d_in[14];
    const float* base   = (const float*)d_in[15];

    const int* src  = eidx;
    const int* dstv = eidx + EE;

    // ---- workspace: hA placed LAST among persistents so layer-1's M can
    //      overlay [hA .. end] (hA is dead in layer 1). Layer-0's M uses
    //      [scratch .. end]. ----
    char* p = (char*)d_ws;
    auto alloc = [&](size_t bytes) {
        char* q = p;
        p += (bytes + 255) & ~(size_t)255;
        return q;
    };
    ushort_t* hB   = (ushort_t*)alloc((size_t)NN * 128 * 2);   // 67.1 MB
    float*    inv  = (float*)alloc((size_t)RR * NN * 4);       // 4.2 MB
    uint_t*   pk   = (uint_t*)alloc((size_t)EE * 4);           // 4.2 MB
    int*      offs = (int*)alloc((size_t)(NN + 1) * 4);        // 1.05 MB
    short*    wbuf = (short*)alloc((size_t)180224 * 2);        // 0.36 MB
    char*     hA_region = p;
    ushort_t* hA   = (ushort_t*)alloc((size_t)NN * 128 * 2);   // 67.1 MB
    char*     scratch = p;                                     // CSR tmp / M0
    uint_t*   cntp = (uint_t*)alloc((size_t)NN * 4);           // dead after CSR
    uchar_t*  rank = (uchar_t*)alloc((size_t)EE);              // dead after CSR
    int*      deg  = (int*)alloc((size_t)NN * 4);              // dead after CSR
    int*      bsum = (int*)alloc((size_t)1024 * 4);            // dead after CSR

    // layer-0 M: scratch..end   (CSR tmps dead before first agg)
    size_t rem0 = (ws_size > (size_t)(scratch - (char*)d_ws))
                      ? (ws_size - (size_t)(scratch - (char*)d_ws)) : 0;
    int cap0 = (int)(rem0 / 1024);            // 1024 B per row (4 planes)
    if (cap0 > NN) cap0 = NN;
    cap0 &= ~127;
    if (cap0 == 0) cap0 = 128;
    // layer-1 M: hA..end        (hA dead in layer 1)
    size_t rem1 = (ws_size > (size_t)(hA_region - (char*)d_ws))
                      ? (ws_size - (size_t)(hA_region - (char*)d_ws)) : 0;
    int cap1 = (int)(rem1 / 1024);
    if (cap1 > NA_) cap1 = NA_;
    cap1 &= ~127;
    if (cap1 == 0) cap1 = 128;

    short* wt_ina = wbuf;
    short* wt_inw = wbuf + 8192;
    auto wt_layer = [&](int l) { return wbuf + 16384 + (size_t)l * 81920; };

    // ---- CSR + inv (packed 8-bit counts, atomic-free placement) ----
    hipMemsetAsync(cntp, 0, (size_t)NN * sizeof(uint_t), stream);
    count_edges<<<EE / 1024, 256, 0, stream>>>(dstv, etype, cntp, rank);
    inv_deg<<<NN / 256, 256, 0, stream>>>(cntp, inv, deg);  // cntp -> prefixes
    scan1<<<NN / 256, 256, 0, stream>>>(deg, offs, bsum);
    scan_bsum<<<1, 256, 0, stream>>>(bsum);
    scan_add<<<NN / 256, 256, 0, stream>>>(offs, bsum);
    place_edges<<<EE / 1024, 256, 0, stream>>>(src, dstv, etype, rank, offs,
                                               cntp, pk);

    prep_weights<<<704, 256, 0, stream>>>(W_in_a, W_in_w, W_root, W_rel, wbuf);

    // ---- input projections ----
    proj_gemm<<<NA_ / 128, 256, 0, stream>>>(x_a, wt_ina, b_in_a, hA);
    proj_gemm<<<NA_ / 128, 256, 0, stream>>>(x_w, wt_inw, b_in_w,
                                             hA + (size_t)NA_ * 128);

    // ---- layers; layer 2 only computes rows < NA and fuses the head ----
    ushort_t* hc = hA;
    ushort_t* hn = hB;
    for (int l = 0; l < 2; l++) {
        int Nout = (l == 0) ? NN : NA_;
        ushort_t* M = (l == 0) ? (ushort_t*)scratch : (ushort_t*)hA_region;
        int cap = (l == 0) ? cap0 : cap1;
        int nch = (Nout + cap - 1) / cap;
        int chunk = ((Nout / nch) + 127) & ~127;        // balanced, x128
        if (chunk > cap) chunk = cap;
        for (int lo = 0; lo < Nout; lo += chunk) {
            int cr = (Nout - lo < chunk) ? (Nout - lo) : chunk;
            agg_means<<<cr / 4, 256, 0, stream>>>(pk, offs, hc, inv, M, lo,
                                                  cap);
            if (l == 0)
                layer_gemm_ln<false><<<cr / 64, 256, 0, stream>>>(
                    M, hc, wt_layer(l), b_conv + l * 128, ln_g + l * 128,
                    ln_b + l * 128, hn, nullptr, nullptr, nullptr, nullptr,
                    lo, cap);
            else
                layer_gemm_ln<true><<<cr / 64, 256, 0, stream>>>(
                    M, hc, wt_layer(l), b_conv + l * 128, ln_g + l * 128,
                    ln_b + l * 128, nullptr, W_out, b_out, base,
                    (float*)d_out, lo, cap);
        }
        ushort_t* t = hc; hc = hn; hn = t;
    }
}

// Round 16
// 540.787 us; speedup vs baseline: 1.7541x; 1.7541x over previous
//
#include <hip/hip_runtime.h>

#define NA_ 131072
#define NN  262144
#define EE  1048576
#define RR  4
#define EPS_ 1e-5f

typedef unsigned short ushort_t;
typedef unsigned char uchar_t;
typedef unsigned int uint_t;
typedef __attribute__((ext_vector_type(8))) short bf16x8;
typedef __attribute__((ext_vector_type(4))) float f32x4;

__device__ __forceinline__ float bf2f(uint_t u16) {
    return __uint_as_float(u16 << 16);
}
__device__ __forceinline__ uint_t f2bf(float f) {
    uint_t x = __float_as_uint(f);
    return (x + 0x7fffu + ((x >> 16) & 1u)) >> 16;   // RNE
}

// async global->LDS DMA, 16 B per lane; LDS dest is base + lane*16 (wave-
// uniform base), but the SOURCE address is per-lane -> swizzle lives there.
__device__ __forceinline__ void gl2lds16(const void* g, void* l) {
    __builtin_amdgcn_global_load_lds(
        (const __attribute__((address_space(1))) void*)g,
        (__attribute__((address_space(3))) void*)l, 16, 0, 0);
}

// ---------------------------------------------------------------------------
// Input projection GEMM: C[M x 128] = relu(A[M x 64] @ B + b)
// ---------------------------------------------------------------------------
__global__ __launch_bounds__(256) void proj_gemm(const float* __restrict__ A,
                                                 const short* __restrict__ Btg,
                                                 const float* __restrict__ bias,
                                                 ushort_t* __restrict__ C) {
    const int K = 64;
    __shared__ short As[128][K + 8];
    __shared__ short Bs[128][K + 8];
    const int tid  = threadIdx.x;
    const int lane = tid & 63;
    const int l15  = lane & 15;
    const int q    = lane >> 4;
    const int wv   = tid >> 6;
    const int wr   = (wv >> 1) * 64;
    const int wc   = (wv & 1) * 64;
    const size_t blockRow = (size_t)blockIdx.x * 128;

    #pragma unroll
    for (int it = 0; it < 4; it++) {
        int sidx = (it * 256 + tid) * 8;
        int row = sidx / K, col = sidx % K;
        const float* Ag = A + (blockRow + row) * K + col;
        float4 v0 = *(const float4*)Ag;
        float4 v1 = *(const float4*)(Ag + 4);
        uint4 u;
        u.x = f2bf(v0.x) | (f2bf(v0.y) << 16);
        u.y = f2bf(v0.z) | (f2bf(v0.w) << 16);
        u.z = f2bf(v1.x) | (f2bf(v1.y) << 16);
        u.w = f2bf(v1.z) | (f2bf(v1.w) << 16);
        *(uint4*)&As[row][col] = u;
        *(uint4*)&Bs[row][col] = *(const uint4*)(Btg + (size_t)row * K + col);
    }
    __syncthreads();

    f32x4 acc[4][4];
    #pragma unroll
    for (int i = 0; i < 4; i++)
        #pragma unroll
        for (int j = 0; j < 4; j++) {
            acc[i][j][0] = 0.f; acc[i][j][1] = 0.f;
            acc[i][j][2] = 0.f; acc[i][j][3] = 0.f;
        }

    #pragma unroll
    for (int kk = 0; kk < 2; kk++) {
        bf16x8 af[4], bfr[4];
        #pragma unroll
        for (int i = 0; i < 4; i++)
            af[i] = *(const bf16x8*)&As[wr + i * 16 + l15][kk * 32 + q * 8];
        #pragma unroll
        for (int j = 0; j < 4; j++)
            bfr[j] = *(const bf16x8*)&Bs[wc + j * 16 + l15][kk * 32 + q * 8];
        #pragma unroll
        for (int i = 0; i < 4; i++)
            #pragma unroll
            for (int j = 0; j < 4; j++)
                acc[i][j] = __builtin_amdgcn_mfma_f32_16x16x32_bf16(
                    af[i], bfr[j], acc[i][j], 0, 0, 0);
    }

    #pragma unroll
    for (int j = 0; j < 4; j++) {
        int gcol = wc + j * 16 + l15;
        float bv = bias[gcol];
        #pragma unroll
        for (int i = 0; i < 4; i++) {
            size_t rbase = blockRow + wr + i * 16 + q * 4;
            #pragma unroll
            for (int r = 0; r < 4; r++) {
                float v = fmaxf(acc[i][j][r] + bv, 0.f);
                C[(rbase + r) * 128 + gcol] = (ushort_t)f2bf(v);
            }
        }
    }
}

// ---------------------------------------------------------------------------
// Weight prep. Input-proj: [n][64]. Layer weights: plain chunk-major
// [kc][n][128] (kc 0..3 = rel, 4 = root). Swizzle is applied at DMA time.
// ---------------------------------------------------------------------------
__global__ void prep_weights(const float* __restrict__ Wia,
                             const float* __restrict__ Wiw,
                             const float* __restrict__ Wroot,
                             const float* __restrict__ Wrel,
                             short* __restrict__ wt) {
    int e = blockIdx.x * 256 + threadIdx.x;
    if (e < 8192) {
        int k = e >> 7, n = e & 127;
        wt[n * 64 + k] = (short)f2bf(Wia[e]);
    } else if (e < 16384) {
        int t = e - 8192;
        int k = t >> 7, n = t & 127;
        wt[8192 + n * 64 + k] = (short)f2bf(Wiw[t]);
    } else {
        int t = e - 16384;           // 0 .. 163839
        int l = t / 81920;
        int d = t % 81920;
        int kc = d / 16384;
        int rem2 = d % 16384;
        int n = rem2 >> 7;
        int kkk = rem2 & 127;
        float val = (kc < 4)
            ? Wrel[(((size_t)l * 4 + kc) * 128 + kkk) * 128 + n]
            : Wroot[((size_t)l * 128 + kkk) * 128 + n];
        wt[16384 + (size_t)l * 81920 + kc * 16384 + n * 128 + kkk] =
            (short)f2bf(val);
    }
}

// ---------------------------------------------------------------------------
// CSR build. Packed 8-bit per-relation counts; 4 edges/thread for atomic ILP.
// ---------------------------------------------------------------------------
__global__ void count_edges(const int* __restrict__ dstv,
                            const int* __restrict__ et,
                            uint_t* __restrict__ cntp,
                            uchar_t* __restrict__ rank) {
    int base = blockIdx.x * 1024 + threadIdx.x;
    int e0 = base, e1 = base + 256, e2 = base + 512, e3 = base + 768;
    int r0 = et[e0], r1 = et[e1], r2 = et[e2], r3 = et[e3];
    int d0 = dstv[e0], d1 = dstv[e1], d2 = dstv[e2], d3 = dstv[e3];
    uint_t o0 = atomicAdd(&cntp[d0], 1u << (8 * r0));
    uint_t o1 = atomicAdd(&cntp[d1], 1u << (8 * r1));
    uint_t o2 = atomicAdd(&cntp[d2], 1u << (8 * r2));
    uint_t o3 = atomicAdd(&cntp[d3], 1u << (8 * r3));
    rank[e0] = (uchar_t)((o0 >> (8 * r0)) & 0xffu);
    rank[e1] = (uchar_t)((o1 >> (8 * r1)) & 0xffu);
    rank[e2] = (uchar_t)((o2 >> (8 * r2)) & 0xffu);
    rank[e3] = (uchar_t)((o3 >> (8 * r3)) & 0xffu);
}

__global__ void inv_deg(uint_t* __restrict__ cntp, float* __restrict__ inv,
                        int* __restrict__ deg) {
    int i = blockIdx.x * 256 + threadIdx.x;
    if (i < NN) {
        uint_t c = cntp[i];
        int c0 = c & 255, c1 = (c >> 8) & 255, c2 = (c >> 16) & 255, c3 = c >> 24;
        inv[i]          = 1.0f / (float)(c0 > 1 ? c0 : 1);
        inv[NN + i]     = 1.0f / (float)(c1 > 1 ? c1 : 1);
        inv[2 * NN + i] = 1.0f / (float)(c2 > 1 ? c2 : 1);
        inv[3 * NN + i] = 1.0f / (float)(c3 > 1 ? c3 : 1);
        deg[i] = c0 + c1 + c2 + c3;
        cntp[i] = ((uint_t)c0 << 8) | ((uint_t)(c0 + c1) << 16)
                | ((uint_t)(c0 + c1 + c2) << 24);
    }
}

__global__ void scan1(const int* __restrict__ deg, int* __restrict__ offs,
                      int* __restrict__ bsum) {
    __shared__ int lds[256];
    int tid = threadIdx.x;
    int i = blockIdx.x * 256 + tid;
    int v = deg[i];
    int incl = v;
    lds[tid] = incl;
    __syncthreads();
    for (int off = 1; off < 256; off <<= 1) {
        int t = (tid >= off) ? lds[tid - off] : 0;
        __syncthreads();
        incl += t;
        lds[tid] = incl;
        __syncthreads();
    }
    offs[i] = incl - v;
    if (tid == 255) bsum[blockIdx.x] = incl;
}

__global__ void scan_bsum(int* __restrict__ bsum) {
    __shared__ int lds[256];
    int tid = threadIdx.x;
    int t0 = bsum[tid * 4 + 0], t1 = bsum[tid * 4 + 1];
    int t2 = bsum[tid * 4 + 2], t3 = bsum[tid * 4 + 3];
    int s = t0 + t1 + t2 + t3;
    int incl = s;
    lds[tid] = incl;
    __syncthreads();
    for (int off = 1; off < 256; off <<= 1) {
        int t = (tid >= off) ? lds[tid - off] : 0;
        __syncthreads();
        incl += t;
        lds[tid] = incl;
        __syncthreads();
    }
    int e = incl - s;
    bsum[tid * 4 + 0] = e;
    bsum[tid * 4 + 1] = e + t0;
    bsum[tid * 4 + 2] = e + t0 + t1;
    bsum[tid * 4 + 3] = e + t0 + t1 + t2;
}

__global__ void scan_add(int* __restrict__ offs, const int* __restrict__ bsum) {
    int i = blockIdx.x * 256 + threadIdx.x;
    offs[i] = offs[i] + bsum[blockIdx.x];
    if (i == 0) offs[NN] = EE;
}

__global__ void place_edges(const int* __restrict__ srcv,
                            const int* __restrict__ dstv,
                            const int* __restrict__ et,
                            const uchar_t* __restrict__ rank,
                            const int* __restrict__ offs,
                            const uint_t* __restrict__ pref,
                            uint_t* __restrict__ pk) {
    int base = blockIdx.x * 1024 + threadIdx.x;
    #pragma unroll
    for (int t = 0; t < 4; t++) {
        int e = base + t * 256;
        int d = dstv[e], r = et[e];
        int pos = offs[d] + (int)((pref[d] >> (8 * r)) & 255u) + (int)rank[e];
        pk[pos] = (uint_t)srcv[e] | ((uint_t)r << 18);
    }
}

// ---------------------------------------------------------------------------
// Pull aggregation (r14-exact, known-good): one wave per dst node. 8/4-wide
// batched gathers, BRANCHLESS relation select (cndmask chain — r15 showed
// any control flow inside the load batch causes catastrophic spill).
// M plane-major, coalesced writes.
// ---------------------------------------------------------------------------
__global__ __launch_bounds__(256) void agg_means(const uint_t* __restrict__ pk,
                                                 const int* __restrict__ offs,
                                                 const ushort_t* __restrict__ hold,
                                                 const float* __restrict__ inv,
                                                 ushort_t* __restrict__ M,
                                                 int lo, int rowsCap) {
    int idx = blockIdx.x * 4 + (threadIdx.x >> 6);
    int d = lo + idx;
    int lane = threadIdx.x & 63;
    int beg = offs[d], end = offs[d + 1];

    float a0x = 0.f, a0y = 0.f, a1x = 0.f, a1y = 0.f;
    float a2x = 0.f, a2y = 0.f, a3x = 0.f, a3y = 0.f;

    auto acc = [&](uint_t p, uint_t hv) {
        float x = bf2f(hv & 0xffffu), y = bf2f(hv >> 16);
        uint_t r = p >> 18;
        a0x += (r == 0) ? x : 0.f;  a0y += (r == 0) ? y : 0.f;
        a1x += (r == 1) ? x : 0.f;  a1y += (r == 1) ? y : 0.f;
        a2x += (r == 2) ? x : 0.f;  a2y += (r == 2) ? y : 0.f;
        a3x += (r == 3) ? x : 0.f;  a3y += (r == 3) ? y : 0.f;
    };

    int e = beg;
    for (; e + 8 <= end; e += 8) {
        uint_t p[8], v[8];
        #pragma unroll
        for (int t = 0; t < 8; t++) p[t] = pk[e + t];
        #pragma unroll
        for (int t = 0; t < 8; t++)
            v[t] = ((const uint_t*)(hold + (size_t)(p[t] & 0x3FFFFu) * 128))[lane];
        #pragma unroll
        for (int t = 0; t < 8; t++) acc(p[t], v[t]);
    }
    for (; e + 4 <= end; e += 4) {
        uint_t p0 = pk[e], p1 = pk[e + 1], p2 = pk[e + 2], p3 = pk[e + 3];
        uint_t v0 = ((const uint_t*)(hold + (size_t)(p0 & 0x3FFFFu) * 128))[lane];
        uint_t v1 = ((const uint_t*)(hold + (size_t)(p1 & 0x3FFFFu) * 128))[lane];
        uint_t v2 = ((const uint_t*)(hold + (size_t)(p2 & 0x3FFFFu) * 128))[lane];
        uint_t v3 = ((const uint_t*)(hold + (size_t)(p3 & 0x3FFFFu) * 128))[lane];
        acc(p0, v0); acc(p1, v1); acc(p2, v2); acc(p3, v3);
    }
    for (; e < end; e++) {
        uint_t p = pk[e];
        uint_t v = ((const uint_t*)(hold + (size_t)(p & 0x3FFFFu) * 128))[lane];
        acc(p, v);
    }

    float w0 = inv[d], w1 = inv[NN + d], w2 = inv[2 * NN + d], w3 = inv[3 * NN + d];
    uint_t* P = (uint_t*)M;
    size_t planeU = (size_t)rowsCap * 64;
    size_t rowU = (size_t)idx * 64 + lane;
    P[rowU]              = f2bf(a0x * w0) | (f2bf(a0y * w0) << 16);
    P[planeU + rowU]     = f2bf(a1x * w1) | (f2bf(a1y * w1) << 16);
    P[2 * planeU + rowU] = f2bf(a2x * w2) | (f2bf(a2y * w2) << 16);
    P[3 * planeU + rowU] = f2bf(a3x * w3) | (f2bf(a3y * w3) << 16);
}

// ---------------------------------------------------------------------------
// Layer GEMM + LN + ReLU (+ optional fused head). Tile BM=64 x BN=128,
// 49.5 KB LDS -> 3 blocks/CU (r13-verified win). Source-side XOR DMA
// swizzle -> conflict-free ds_reads (r12-verified: conflicts = 0).
// ---------------------------------------------------------------------------
template<bool HEAD>
__global__ __launch_bounds__(256) void layer_gemm_ln(
    const ushort_t* __restrict__ Mg,
    const ushort_t* __restrict__ hold,
    const short* __restrict__ Btg,       // [5][128 n][128 k] chunk-major
    const float* __restrict__ bconv,
    const float* __restrict__ lng,
    const float* __restrict__ lnb,
    ushort_t* __restrict__ hnew,
    const float* __restrict__ Wout,
    const float* __restrict__ bout,
    const float* __restrict__ basep,
    float* __restrict__ pred,
    int lo, int rowsCap) {
    __shared__ short As[64 * 128];       // 16 KB
    __shared__ short Bs[128 * 128];      // 32 KB
    __shared__ float lds_s[64][2], lds_q[64][2], lds_h[64][2];

    const int tid  = threadIdx.x;
    const int lane = tid & 63;
    const int l15  = lane & 15;
    const int q    = lane >> 4;
    const int wv   = tid >> 6;
    const int wr   = (wv >> 1) * 32;     // 2 row-bands of 32
    const int wc   = (wv & 1) * 64;      // 2 col-bands of 64
    const int blockRowL = blockIdx.x * 64;
    const size_t planeS = (size_t)rowsCap * 128;

    f32x4 acc[2][4];
    #pragma unroll
    for (int i = 0; i < 2; i++)
        #pragma unroll
        for (int j = 0; j < 4; j++) {
            acc[i][j][0] = 0.f; acc[i][j][1] = 0.f;
            acc[i][j][2] = 0.f; acc[i][j][3] = 0.f;
        }

    // per-lane source offset with XOR group swizzle (r12-verified).
    const int rloc = lane >> 4;
    const int gsw  = (lane & 15) ^ ((wv * 4 + rloc) & 15);
    const int lby  = (rloc << 8) + (gsw << 4);

    for (int kc = 0; kc < 5; kc++) {
        const char* asrc = (kc < 4)
            ? (const char*)(Mg + (size_t)kc * planeS + (size_t)blockRowL * 128)
            : (const char*)(hold + (size_t)(lo + blockRowL) * 128);
        const char* bsrc = (const char*)(Btg + (size_t)kc * 16384);
        __syncthreads();
        #pragma unroll
        for (int it = 0; it < 8; it++) {
            int off = it * 4096 + wv * 1024;
            if (it < 4) gl2lds16(asrc + off + lby, (char*)As + off);
            gl2lds16(bsrc + off + lby, (char*)Bs + off);
        }
        __syncthreads();

        #pragma unroll
        for (int kk = 0; kk < 4; kk++) {
            bf16x8 af[2], bfr[4];
            #pragma unroll
            for (int i = 0; i < 2; i++)
                af[i] = *(const bf16x8*)
                    &As[(wr + i * 16 + l15) * 128 + (((kk * 4 + q) ^ l15) << 3)];
            #pragma unroll
            for (int j = 0; j < 4; j++)
                bfr[j] = *(const bf16x8*)
                    &Bs[(wc + j * 16 + l15) * 128 + (((kk * 4 + q) ^ l15) << 3)];
            #pragma unroll
            for (int i = 0; i < 2; i++)
                #pragma unroll
                for (int j = 0; j < 4; j++)
                    acc[i][j] = __builtin_amdgcn_mfma_f32_16x16x32_bf16(
                        af[i], bfr[j], acc[i][j], 0, 0, 0);
        }
    }

    // ---- epilogue: + b_conv, LayerNorm, affine, ReLU (+ head dot) ----
    float bj[4], gj[4], bbj[4], wj[4];
    #pragma unroll
    for (int j = 0; j < 4; j++) {
        int col = wc + j * 16 + l15;
        bj[j]  = bconv[col];
        gj[j]  = lng[col];
        bbj[j] = lnb[col];
        if (HEAD) wj[j] = Wout[col];
    }
    #pragma unroll
    for (int i = 0; i < 2; i++)
        #pragma unroll
        for (int j = 0; j < 4; j++)
            #pragma unroll
            for (int r = 0; r < 4; r++) acc[i][j][r] += bj[j];

    float ps[2][4], pq[2][4];
    #pragma unroll
    for (int i = 0; i < 2; i++)
        #pragma unroll
        for (int r = 0; r < 4; r++) {
            float s = 0.f, qq = 0.f;
            #pragma unroll
            for (int j = 0; j < 4; j++) {
                float v = acc[i][j][r];
                s += v;
                qq += v * v;
            }
            ps[i][r] = s;
            pq[i][r] = qq;
        }
    #pragma unroll
    for (int m = 1; m <= 8; m <<= 1)
        #pragma unroll
        for (int i = 0; i < 2; i++)
            #pragma unroll
            for (int r = 0; r < 4; r++) {
                ps[i][r] += __shfl_xor(ps[i][r], m);
                pq[i][r] += __shfl_xor(pq[i][r], m);
            }

    if (l15 == 0) {
        #pragma unroll
        for (int i = 0; i < 2; i++)
            #pragma unroll
            for (int r = 0; r < 4; r++) {
                int row = wr + i * 16 + q * 4 + r;
                lds_s[row][wv & 1] = ps[i][r];
                lds_q[row][wv & 1] = pq[i][r];
            }
    }
    __syncthreads();

    float hs[2][4];
    #pragma unroll
    for (int i = 0; i < 2; i++)
        #pragma unroll
        for (int r = 0; r < 4; r++) {
            int row = wr + i * 16 + q * 4 + r;
            float sum = lds_s[row][0] + lds_s[row][1];
            float sq  = lds_q[row][0] + lds_q[row][1];
            float mu  = sum * (1.0f / 128.0f);
            float var = sq * (1.0f / 128.0f) - mu * mu;
            float rs  = rsqrtf(var + EPS_);
            size_t gr = (size_t)(lo + blockRowL + row) * 128;
            float hd = 0.f;
            #pragma unroll
            for (int j = 0; j < 4; j++) {
                float v = (acc[i][j][r] - mu) * rs * gj[j] + bbj[j];
                v = fmaxf(v, 0.f);
                if (HEAD) hd += v * wj[j];
                else hnew[gr + wc + j * 16 + l15] = (ushort_t)f2bf(v);
            }
            if (HEAD) hs[i][r] = hd;
        }

    if (HEAD) {
        #pragma unroll
        for (int m = 1; m <= 8; m <<= 1)
            #pragma unroll
            for (int i = 0; i < 2; i++)
                #pragma unroll
                for (int r = 0; r < 4; r++)
                    hs[i][r] += __shfl_xor(hs[i][r], m);
        if (l15 == 0) {
            #pragma unroll
            for (int i = 0; i < 2; i++)
                #pragma unroll
                for (int r = 0; r < 4; r++) {
                    int row = wr + i * 16 + q * 4 + r;
                    lds_h[row][wv & 1] = hs[i][r];
                }
        }
        __syncthreads();
        if (tid < 64)
            pred[lo + blockRowL + tid] =
                lds_h[tid][0] + lds_h[tid][1] + bout[0] + basep[0];
    }
}

// ---------------------------------------------------------------------------
extern "C" void kernel_launch(void* const* d_in, const int* in_sizes, int n_in,
                              void* d_out, int out_size, void* d_ws, size_t ws_size,
                              hipStream_t stream) {
    const float* x_a    = (const float*)d_in[0];
    const float* x_w    = (const float*)d_in[1];
    const int*   eidx   = (const int*)d_in[2];
    const int*   etype  = (const int*)d_in[3];
    const float* W_in_a = (const float*)d_in[4];
    const float* b_in_a = (const float*)d_in[5];
    const float* W_in_w = (const float*)d_in[6];
    const float* b_in_w = (const float*)d_in[7];
    const float* W_rel  = (const float*)d_in[8];
    const float* W_root = (const float*)d_in[9];
    const float* b_conv = (const float*)d_in[10];
    const float* ln_g   = (const float*)d_in[11];
    const float* ln_b   = (const float*)d_in[12];
    const float* W_out  = (const float*)d_in[13];
    const float* b_out  = (const float*)d_in[14];
    const float* base   = (const float*)d_in[15];

    const int* src  = eidx;
    const int* dstv = eidx + EE;

    // ---- workspace: hA placed LAST among persistents so layer-1's M can
    //      overlay [hA .. end] (hA is dead in layer 1). Layer-0's M uses
    //      [scratch .. end]. ----
    char* p = (char*)d_ws;
    auto alloc = [&](size_t bytes) {
        char* q = p;
        p += (bytes + 255) & ~(size_t)255;
        return q;
    };
    ushort_t* hB   = (ushort_t*)alloc((size_t)NN * 128 * 2);   // 67.1 MB
    float*    inv  = (float*)alloc((size_t)RR * NN * 4);       // 4.2 MB
    uint_t*   pk   = (uint_t*)alloc((size_t)EE * 4);           // 4.2 MB
    int*      offs = (int*)alloc((size_t)(NN + 1) * 4);        // 1.05 MB
    short*    wbuf = (short*)alloc((size_t)180224 * 2);        // 0.36 MB
    char*     hA_region = p;
    ushort_t* hA   = (ushort_t*)alloc((size_t)NN * 128 * 2);   // 67.1 MB
    char*     scratch = p;                                     // CSR tmp / M0
    uint_t*   cntp = (uint_t*)alloc((size_t)NN * 4);           // dead after CSR
    uchar_t*  rank = (uchar_t*)alloc((size_t)EE);              // dead after CSR
    int*      deg  = (int*)alloc((size_t)NN * 4);              // dead after CSR
    int*      bsum = (int*)alloc((size_t)1024 * 4);            // dead after CSR

    // layer-0 M: scratch..end   (CSR tmps dead before first agg)
    size_t rem0 = (ws_size > (size_t)(scratch - (char*)d_ws))
                      ? (ws_size - (size_t)(scratch - (char*)d_ws)) : 0;
    int cap0 = (int)(rem0 / 1024);            // 1024 B per row (4 planes)
    if (cap0 > NN) cap0 = NN;
    cap0 &= ~127;
    if (cap0 == 0) cap0 = 128;
    // layer-1 M: hA..end        (hA dead in layer 1)
    size_t rem1 = (ws_size > (size_t)(hA_region - (char*)d_ws))
                      ? (ws_size - (size_t)(hA_region - (char*)d_ws)) : 0;
    int cap1 = (int)(rem1 / 1024);
    if (cap1 > NA_) cap1 = NA_;
    cap1 &= ~127;
    if (cap1 == 0) cap1 = 128;

    short* wt_ina = wbuf;
    short* wt_inw = wbuf + 8192;
    auto wt_layer = [&](int l) { return wbuf + 16384 + (size_t)l * 81920; };

    // ---- CSR + inv (packed 8-bit counts, atomic-free placement) ----
    hipMemsetAsync(cntp, 0, (size_t)NN * sizeof(uint_t), stream);
    count_edges<<<EE / 1024, 256, 0, stream>>>(dstv, etype, cntp, rank);
    inv_deg<<<NN / 256, 256, 0, stream>>>(cntp, inv, deg);  // cntp -> prefixes
    scan1<<<NN / 256, 256, 0, stream>>>(deg, offs, bsum);
    scan_bsum<<<1, 256, 0, stream>>>(bsum);
    scan_add<<<NN / 256, 256, 0, stream>>>(offs, bsum);
    place_edges<<<EE / 1024, 256, 0, stream>>>(src, dstv, etype, rank, offs,
                                               cntp, pk);

    prep_weights<<<704, 256, 0, stream>>>(W_in_a, W_in_w, W_root, W_rel, wbuf);

    // ---- input projections ----
    proj_gemm<<<NA_ / 128, 256, 0, stream>>>(x_a, wt_ina, b_in_a, hA);
    proj_gemm<<<NA_ / 128, 256, 0, stream>>>(x_w, wt_inw, b_in_w,
                                             hA + (size_t)NA_ * 128);

    // ---- layers; layer 2 only computes rows < NA and fuses the head ----
    ushort_t* hc = hA;
    ushort_t* hn = hB;
    for (int l = 0; l < 2; l++) {
        int Nout = (l == 0) ? NN : NA_;
        ushort_t* M = (l == 0) ? (ushort_t*)scratch : (ushort_t*)hA_region;
        int cap = (l == 0) ? cap0 : cap1;
        int nch = (Nout + cap - 1) / cap;
        int chunk = ((Nout / nch) + 127) & ~127;        // balanced, x128
        if (chunk > cap) chunk = cap;
        for (int lo = 0; lo < Nout; lo += chunk) {
            int cr = (Nout - lo < chunk) ? (Nout - lo) : chunk;
            agg_means<<<cr / 4, 256, 0, stream>>>(pk, offs, hc, inv, M, lo,
                                                  cap);
            if (l == 0)
                layer_gemm_ln<false><<<cr / 64, 256, 0, stream>>>(
                    M, hc, wt_layer(l), b_conv + l * 128, ln_g + l * 128,
                    ln_b + l * 128, hn, nullptr, nullptr, nullptr, nullptr,
                    lo, cap);
            else
                layer_gemm_ln<true><<<cr / 64, 256, 0, stream>>>(
                    M, hc, wt_layer(l), b_conv + l * 128, ln_g + l * 128,
                    ln_b + l * 128, nullptr, W_out, b_out, base,
                    (float*)d_out, lo, cap);
        }
        ushort_t* t = hc; hc = hn; hn = t;
    }
}